// Round 16
// baseline (329.066 us; speedup 1.0000x reference)
//
#include <hip/hip_runtime.h>

#define TS 1000

typedef _Float16 half2v __attribute__((ext_vector_type(2)));

__device__ __forceinline__ int rli(int v, int l) {
    return __builtin_amdgcn_readlane(v, l);
}
__device__ __forceinline__ float fsig(float x) {
    return __builtin_amdgcn_rcpf(1.0f + __expf(-x));
}
__device__ __forceinline__ float ftanh(float x) {
    return 1.0f - 2.0f * __builtin_amdgcn_rcpf(1.0f + __expf(2.0f * x));
}

// Round-14 structure (best: 332 us kernel, single-owner consumer, unified
// f16-dot2 reg shape) + 3 latency deltas on the consumer's serial path:
//   (1) all 32 v_readlane broadcasts batched into SGPRs BEFORE the dot2
//       block, separated by sched_barrier(0) — kills VALU-writes-SGPR ->
//       VALU-reads-SGPR hazard stalls that an interleaved schedule pays
//       32x per step.
//   (2) h/x pair packed with ONE v_cvt_pkrtz_f16_f32 via inline asm
//       (round 15's builtin had a return-type mismatch; asm avoids it).
//   (3) the window's 4 psum ds_read_b128 hoisted to just after the
//       barrier, out of the per-step chain.
// Roles per block (one (g,b) chain, 8 waves):
//   w0 = consumer (sole h owner), w1,w2,w3,w5 = producers (one full gx
//   step each, 2 windows ahead), w4,w6,w7 = barrier participants.
// One NON-draining s_barrier per 4-step window; x loads in flight across
// it (tied s_waitcnt vmcnt). psum ring: slot (w+2)&3 written pre-b(w),
// read during w+2, rewritten pre-b(w+4) — >=1 barrier both ways.
// Single h owner -> bitwise deterministic across graph replays.
__global__ __launch_bounds__(512)
__attribute__((amdgpu_waves_per_eu(2, 2)))
void gru_uni(const float* __restrict__ x, const float* __restrict__ h0,
             const float* __restrict__ W, const float* __restrict__ U,
             const float* __restrict__ bi, const float* __restrict__ bh,
             float* __restrict__ out, float* __restrict__ hout)
{
    __shared__ float4 psum[4][4][64];    // [slot][step j][lane], 16 KB

    const int tid  = threadIdx.x;
    const int lane = tid & 63;
    const int wid  = tid >> 6;
    const bool cons = (wid == 0);
    const bool prod = (wid == 1) | (wid == 2) | (wid == 3) | (wid == 5);
    const int jmap = (wid == 5) ? 3 : (wid - 1);     // producer step index

    const int g = blockIdx.x >> 5, b = blockIdx.x & 31;

    // ---- unified weight pack: 96 half2 dwords/lane (w0: U, others: W).
    int uw[96];                  // [gate*32 + k2] = half2(M[2k2], M[2k2+1])
    {
        const float* Pg = (cons ? U : W) + (size_t)g * (64 * 192) + lane;
        #pragma unroll
        for (int k2 = 0; k2 < 32; ++k2) {
            #pragma unroll
            for (int gate = 0; gate < 3; ++gate) {
                const float a = Pg[(2 * k2) * 192 + gate * 64];
                const float c = Pg[(2 * k2 + 1) * 192 + gate * 64];
                half2v p; p.x = (_Float16)a; p.y = (_Float16)c;   // RNE
                uw[gate * 32 + k2] = __builtin_bit_cast(int, p);
            }
        }
    }
    #pragma unroll
    for (int k2 = 0; k2 < 32; ++k2)
        asm volatile("" : "+v"(uw[k2]), "+v"(uw[32 + k2]), "+v"(uw[64 + k2]));

    // f32 biases: consumer = b_h, producers = b_i (accumulator init).
    float b0 = 0.f, b1 = 0.f, b2 = 0.f;
    {
        const float* bb = (cons ? bh : bi) + g * 192 + lane;
        b0 = bb[0]; b1 = bb[64]; b2 = bb[128];
    }

    float h = 0.f;
    if (cons) h = h0[(g * 32 + b) * 64 + lane];

    const float* xp = x + (size_t)b * (TS * 512) + g * 64 + lane;
    float* op = out + (size_t)b * (TS * 512) + g * 64 + lane;

// pack src pair via DPP xor-1 + one v_cvt_pkrtz_f16_f32 (asm, int result);
// 32 readlanes batched to SGPRs; sched_barrier; 96 dot2 (f32 acc, 6-way ILP).
#define MATVEC(SRCV, OZ, OR, ON)                                              \
    {                                                                         \
        const int sxi_ = __builtin_amdgcn_update_dpp(                         \
            0, __float_as_int(SRCV), 0xB1, 0xF, 0xF, true);                   \
        int spi_;                                                             \
        asm("v_cvt_pkrtz_f16_f32 %0, %1, %2"                                  \
            : "=v"(spi_) : "v"(SRCV), "v"(__int_as_float(sxi_)));             \
        int hs_[32];                                                          \
        _Pragma("unroll")                                                     \
        for (int k2 = 0; k2 < 32; ++k2) hs_[k2] = rli(spi_, 2 * k2);          \
        __builtin_amdgcn_sched_barrier(0);                                    \
        float _az = b0, _ar = b1, _an = b2, _az2 = 0.f, _ar2 = 0.f, _an2 = 0.f; \
        _Pragma("unroll")                                                     \
        for (int k2 = 0; k2 < 16; ++k2) {                                     \
            const half2v hv_ = __builtin_bit_cast(half2v, hs_[k2]);           \
            _az = __builtin_amdgcn_fdot2(__builtin_bit_cast(half2v, uw[k2]),      hv_, _az, false); \
            _ar = __builtin_amdgcn_fdot2(__builtin_bit_cast(half2v, uw[32 + k2]), hv_, _ar, false); \
            _an = __builtin_amdgcn_fdot2(__builtin_bit_cast(half2v, uw[64 + k2]), hv_, _an, false); \
        }                                                                     \
        _Pragma("unroll")                                                     \
        for (int k2 = 16; k2 < 32; ++k2) {                                    \
            const half2v hv_ = __builtin_bit_cast(half2v, hs_[k2]);           \
            _az2 = __builtin_amdgcn_fdot2(__builtin_bit_cast(half2v, uw[k2]),      hv_, _az2, false); \
            _ar2 = __builtin_amdgcn_fdot2(__builtin_bit_cast(half2v, uw[32 + k2]), hv_, _ar2, false); \
            _an2 = __builtin_amdgcn_fdot2(__builtin_bit_cast(half2v, uw[64 + k2]), hv_, _an2, false); \
        }                                                                     \
        OZ = _az + _az2; OR = _ar + _ar2; ON = _an + _an2;                    \
    }

#define XLOAD(DST, T_)                                                        \
    { const float* pp_ = xp + (size_t)(T_) * 512;                             \
      asm volatile("global_load_dword %0, %1, off" : "=v"(DST) : "v"(pp_)); }

#define PSTEP(XS, WR)                                                         \
    {                                                                         \
        float pz_, pr_, pn_;                                                  \
        MATVEC(XS, pz_, pr_, pn_)                                             \
        psum[WR][jmap][lane] = make_float4(pz_, pr_, pn_, 0.f);               \
    }

#define CSTEP(Q)                                                              \
    {                                                                         \
        float ghz, ghr, ghn;                                                  \
        MATVEC(h, ghz, ghr, ghn)                                              \
        const float z = fsig((Q).x + ghz);                                    \
        const float r = fsig((Q).y + ghr);                                    \
        const float n = ftanh(fmaf(r, ghn, (Q).z));   /* reset_after */       \
        h = n + z * (h - n);                                                  \
        op[0] = h; op += 512;                                                 \
    }

    // ---- prologue: psum[0] (steps 0-3), psum[1] (steps 4-7); x(8+j) in flight.
    float xa = 0.f, xb = 0.f;
    if (prod) {
        XLOAD(xa, jmap) XLOAD(xb, 4 + jmap)
        asm volatile("s_waitcnt vmcnt(0)" : "+v"(xa), "+v"(xb));
        PSTEP(xa, 0)
        PSTEP(xb, 1)
        XLOAD(xa, 8 + jmap)
    }
    asm volatile("s_waitcnt lgkmcnt(0)" ::: "memory");
    __builtin_amdgcn_s_barrier();

#define WINDOW(P, XU, XF)                                                     \
    {                                                                         \
        const int w  = dw * 2 + (P);                                          \
        const int rd = w & 3;                                                 \
        const int wr = (w + 2) & 3;                                           \
        if (cons) {                                                           \
            /* hoisted: all 4 psum reads issue up front, out of the chain */  \
            const float4 q0_ = psum[rd][0][lane];                             \
            const float4 q1_ = psum[rd][1][lane];                             \
            const float4 q2_ = psum[rd][2][lane];                             \
            const float4 q3_ = psum[rd][3][lane];                             \
            CSTEP(q0_) CSTEP(q1_) CSTEP(q2_) CSTEP(q3_)                       \
        } else if (prod) {                                                    \
            int tl = 4 * (w + 3) + jmap; if (tl > TS - 1) tl = TS - 1;        \
            XLOAD(XF, tl)                                                     \
            asm volatile("s_waitcnt vmcnt(1)" : "+v"(XU));                    \
            PSTEP(XU, wr)                                                     \
        }                                                                     \
        asm volatile("s_waitcnt lgkmcnt(0)" ::: "memory");                    \
        __builtin_amdgcn_sched_barrier(0);                                    \
        __builtin_amdgcn_s_barrier();          /* NO vmcnt drain */           \
        __builtin_amdgcn_sched_barrier(0);                                    \
    }

    for (int dw = 0; dw < 125; ++dw) {
        WINDOW(0, xa, xb)
        WINDOW(1, xb, xa)
    }
#undef WINDOW
#undef CSTEP
#undef PSTEP
#undef XLOAD
#undef MATVEC

    if (cons)
        hout[(g * 32 + b) * 64 + lane] = h;
}

extern "C" void kernel_launch(void* const* d_in, const int* in_sizes, int n_in,
                              void* d_out, int out_size, void* d_ws, size_t ws_size,
                              hipStream_t stream) {
    const float* x  = (const float*)d_in[0];
    const float* h0 = (const float*)d_in[1];
    const float* W  = (const float*)d_in[2];
    const float* U  = (const float*)d_in[3];
    const float* bi = (const float*)d_in[4];
    const float* bh = (const float*)d_in[5];
    float* out  = (float*)d_out;
    float* hout = out + (size_t)32 * TS * 512;
    hipLaunchKernelGGL(gru_uni, dim3(256), dim3(512), 0, stream,
                       x, h0, W, U, bi, bh, out, hout);
}

// Round 17
// 317.926 us; speedup vs baseline: 1.0350x; 1.0350x over previous
//
#include <hip/hip_runtime.h>

#define TS 1000

typedef _Float16 half2v __attribute__((ext_vector_type(2)));

__device__ __forceinline__ int rli(int v, int l) {
    return __builtin_amdgcn_readlane(v, l);
}
__device__ __forceinline__ float fsig(float x) {
    return __builtin_amdgcn_rcpf(1.0f + __expf(-x));
}
__device__ __forceinline__ float ftanh(float x) {
    return 1.0f - 2.0f * __builtin_amdgcn_rcpf(1.0f + __expf(2.0f * x));
}

// FINAL CONFIG = round-14 kernel verbatim (best measured: 332 us kernel,
// 318.6 us total, VGPR 96 no-spill, absmax 0.0078 stable).
// Round-15/16 latency deltas (SGPR readlane batching, pkrtz pack, psum
// hoisting) measured collectively neutral-to-negative (+8 us) -> reverted.
//
// One block per (g,b) chain, 8 waves, ONE code shape for all roles:
//   every active wave holds 96 packed-half2 weight dwords (w0: U-f16,
//   others: W-f16) and runs the SAME 32-readlane + 96-dot2 matvec
//   (f32 accumulate; only inputs rounded to f16).
//   w0          = consumer: U·h(t) + gates + h-update (sole h owner).
//   w1,w2,w3,w5 = producers: producer j computes the FULL gx(step) for
//                 step 4(w+2)+j alone, writes psum[(w+2)&3][j] directly.
//   w4,w6,w7    = barrier participants only (consumer alone on SIMD0).
// One NON-draining s_barrier per 4-step window; x loads in flight across
// it (2-deep per producer, tied s_waitcnt vmcnt(1)).
// psum ring audit (single writer per slot): slot (w+2)&3 written pre-b(w),
// read by consumer during w+2 (after b(w), b(w+1)), rewritten pre-b(w+4)
// (after the read's barrier b(w+2)). >=1 barrier both ways.
// Single h owner -> bitwise deterministic across graph replays.
__global__ __launch_bounds__(512)
__attribute__((amdgpu_waves_per_eu(2, 2)))
void gru_uni(const float* __restrict__ x, const float* __restrict__ h0,
             const float* __restrict__ W, const float* __restrict__ U,
             const float* __restrict__ bi, const float* __restrict__ bh,
             float* __restrict__ out, float* __restrict__ hout)
{
    __shared__ float4 psum[4][4][64];    // [slot][step j][lane], 16 KB

    const int tid  = threadIdx.x;
    const int lane = tid & 63;
    const int wid  = tid >> 6;
    const bool cons = (wid == 0);
    const bool prod = (wid == 1) | (wid == 2) | (wid == 3) | (wid == 5);
    const int jmap = (wid == 5) ? 3 : (wid - 1);     // producer step index

    const int g = blockIdx.x >> 5, b = blockIdx.x & 31;

    // ---- unified weight pack: 96 half2 dwords/lane (w0: U, others: W).
    int uw[96];                  // [gate*32 + k2] = half2(M[2k2], M[2k2+1])
    {
        const float* Pg = (cons ? U : W) + (size_t)g * (64 * 192) + lane;
        #pragma unroll
        for (int k2 = 0; k2 < 32; ++k2) {
            #pragma unroll
            for (int gate = 0; gate < 3; ++gate) {
                const float a = Pg[(2 * k2) * 192 + gate * 64];
                const float c = Pg[(2 * k2 + 1) * 192 + gate * 64];
                half2v p; p.x = (_Float16)a; p.y = (_Float16)c;   // RNE
                uw[gate * 32 + k2] = __builtin_bit_cast(int, p);
            }
        }
    }
    #pragma unroll
    for (int k2 = 0; k2 < 32; ++k2)
        asm volatile("" : "+v"(uw[k2]), "+v"(uw[32 + k2]), "+v"(uw[64 + k2]));

    // f32 biases: consumer = b_h, producers = b_i (accumulator init).
    float b0 = 0.f, b1 = 0.f, b2 = 0.f;
    {
        const float* bb = (cons ? bh : bi) + g * 192 + lane;
        b0 = bb[0]; b1 = bb[64]; b2 = bb[128];
    }

    float h = 0.f;
    if (cons) h = h0[(g * 32 + b) * 64 + lane];

    const float* xp = x + (size_t)b * (TS * 512) + g * 64 + lane;
    float* op = out + (size_t)b * (TS * 512) + g * 64 + lane;

// pack src pair via DPP xor-1 lane swap, then 32 readlane + 96 dot2 (f32 acc)
#define MATVEC(SRCV, OZ, OR, ON)                                              \
    {                                                                         \
        const int sxi_ = __builtin_amdgcn_update_dpp(                         \
            0, __float_as_int(SRCV), 0xB1, 0xF, 0xF, true);                   \
        half2v sp_; sp_.x = (_Float16)(SRCV);                                 \
        sp_.y = (_Float16)__int_as_float(sxi_);                               \
        const int spi_ = __builtin_bit_cast(int, sp_);                        \
        float _az = b0, _ar = b1, _an = b2, _az2 = 0.f, _ar2 = 0.f, _an2 = 0.f; \
        _Pragma("unroll")                                                     \
        for (int k2 = 0; k2 < 16; ++k2) {                                     \
            const half2v hv_ = __builtin_bit_cast(half2v, rli(spi_, 2 * k2)); \
            _az = __builtin_amdgcn_fdot2(__builtin_bit_cast(half2v, uw[k2]),      hv_, _az, false); \
            _ar = __builtin_amdgcn_fdot2(__builtin_bit_cast(half2v, uw[32 + k2]), hv_, _ar, false); \
            _an = __builtin_amdgcn_fdot2(__builtin_bit_cast(half2v, uw[64 + k2]), hv_, _an, false); \
        }                                                                     \
        _Pragma("unroll")                                                     \
        for (int k2 = 16; k2 < 32; ++k2) {                                    \
            const half2v hv_ = __builtin_bit_cast(half2v, rli(spi_, 2 * k2)); \
            _az2 = __builtin_amdgcn_fdot2(__builtin_bit_cast(half2v, uw[k2]),      hv_, _az2, false); \
            _ar2 = __builtin_amdgcn_fdot2(__builtin_bit_cast(half2v, uw[32 + k2]), hv_, _ar2, false); \
            _an2 = __builtin_amdgcn_fdot2(__builtin_bit_cast(half2v, uw[64 + k2]), hv_, _an2, false); \
        }                                                                     \
        OZ = _az + _az2; OR = _ar + _ar2; ON = _an + _an2;                    \
    }

#define XLOAD(DST, T_)                                                        \
    { const float* pp_ = xp + (size_t)(T_) * 512;                             \
      asm volatile("global_load_dword %0, %1, off" : "=v"(DST) : "v"(pp_)); }

#define PSTEP(XS, WR)                                                         \
    {                                                                         \
        float pz_, pr_, pn_;                                                  \
        MATVEC(XS, pz_, pr_, pn_)                                             \
        psum[WR][jmap][lane] = make_float4(pz_, pr_, pn_, 0.f);               \
    }

#define CSTEP(RD, J)                                                          \
    {                                                                         \
        const float4 q = psum[RD][J][lane];                                   \
        float ghz, ghr, ghn;                                                  \
        MATVEC(h, ghz, ghr, ghn)                                              \
        const float z = fsig(q.x + ghz);                                      \
        const float r = fsig(q.y + ghr);                                      \
        const float n = ftanh(fmaf(r, ghn, q.z));   /* reset_after */         \
        h = n + z * (h - n);                                                  \
        op[0] = h; op += 512;                                                 \
    }

    // ---- prologue: psum[0] (steps 0-3), psum[1] (steps 4-7); x(8+j) in flight.
    float xa = 0.f, xb = 0.f;
    if (prod) {
        XLOAD(xa, jmap) XLOAD(xb, 4 + jmap)
        asm volatile("s_waitcnt vmcnt(0)" : "+v"(xa), "+v"(xb));
        PSTEP(xa, 0)
        PSTEP(xb, 1)
        XLOAD(xa, 8 + jmap)
    }
    asm volatile("s_waitcnt lgkmcnt(0)" ::: "memory");
    __builtin_amdgcn_s_barrier();

#define WINDOW(P, XU, XF)                                                     \
    {                                                                         \
        const int w  = dw * 2 + (P);                                          \
        const int rd = w & 3;                                                 \
        const int wr = (w + 2) & 3;                                           \
        if (cons) {                                                           \
            CSTEP(rd, 0) CSTEP(rd, 1) CSTEP(rd, 2) CSTEP(rd, 3)               \
        } else if (prod) {                                                    \
            int tl = 4 * (w + 3) + jmap; if (tl > TS - 1) tl = TS - 1;        \
            XLOAD(XF, tl)                                                     \
            asm volatile("s_waitcnt vmcnt(1)" : "+v"(XU));                    \
            PSTEP(XU, wr)                                                     \
        }                                                                     \
        asm volatile("s_waitcnt lgkmcnt(0)" ::: "memory");                    \
        __builtin_amdgcn_sched_barrier(0);                                    \
        __builtin_amdgcn_s_barrier();          /* NO vmcnt drain */           \
        __builtin_amdgcn_sched_barrier(0);                                    \
    }

    for (int dw = 0; dw < 125; ++dw) {
        WINDOW(0, xa, xb)
        WINDOW(1, xb, xa)
    }
#undef WINDOW
#undef CSTEP
#undef PSTEP
#undef XLOAD
#undef MATVEC

    if (cons)
        hout[(g * 32 + b) * 64 + lane] = h;
}

extern "C" void kernel_launch(void* const* d_in, const int* in_sizes, int n_in,
                              void* d_out, int out_size, void* d_ws, size_t ws_size,
                              hipStream_t stream) {
    const float* x  = (const float*)d_in[0];
    const float* h0 = (const float*)d_in[1];
    const float* W  = (const float*)d_in[2];
    const float* U  = (const float*)d_in[3];
    const float* bi = (const float*)d_in[4];
    const float* bh = (const float*)d_in[5];
    float* out  = (float*)d_out;
    float* hout = out + (size_t)32 * TS * 512;
    hipLaunchKernelGGL(gru_uni, dim3(256), dim3(512), 0, stream,
                       x, h0, W, U, bi, bh, out, hout);
}